// Round 13
// baseline (3383.168 us; speedup 1.0000x reference)
//
#include <hip/hip_runtime.h>

#define NZg  512
#define NXg  512
#define NT   1200
#define NSRC 4
#define NREC 512
#define DTC  0.001f
#define DHC  10.0f

#define TT     16            // interior tile per WAVE
#define KK     16            // substeps per batch (= halo width), even
#define NBATCH 75            // NT / KK
#define NTH    256           // 4 waves per block, 1 block/CU
#define NBZ    16            // block grid (16x16 blocks of 32x32 interior)
#define NBX    16
#define NBLK   256
#define EE     48            // extended tile = TT + 2*KK
#define EPAD   49            // padded LDS row stride (u64) for staging
#define NST    36            // staging iterations: 48*48/64
#define CPAD   17            // padded stride for 16x16 store-back staging

typedef unsigned long long u64;

__device__ __forceinline__ u64 ld_agent(const u64* p) {
    return __hip_atomic_load(p, __ATOMIC_RELAXED, __HIP_MEMORY_SCOPE_AGENT);
}
__device__ __forceinline__ void st_agent(u64* p, u64 v) {
    __hip_atomic_store(p, v, __ATOMIC_RELAXED, __HIP_MEMORY_SCOPE_AGENT);
}
__device__ __forceinline__ int ld_flag(const int* p) {
    return __hip_atomic_load(p, __ATOMIC_RELAXED, __HIP_MEMORY_SCOPE_AGENT);
}
__device__ __forceinline__ void st_flag(int* p, int v) {
    __hip_atomic_store(p, v, __ATOMIC_RELAXED, __HIP_MEMORY_SCOPE_AGENT);
}
__device__ __forceinline__ u64 pack2(float a, float b) {
    union { float f[2]; u64 u; } c; c.f[0] = a; c.f[1] = b; return c.u;
}
__device__ __forceinline__ float2 unpack2(u64 v) {
    union { u64 u; float f[2]; } c; c.u = v; return make_float2(c.f[0], c.f[1]);
}

// Static-tree cell pick: ce is runtime, loop indices compile-time.
#define PICK(PRa, ce, vout)                                                  \
    { vout = 0.f;                                                            \
      _Pragma("unroll") for (int i_ = 0; i_ < 3; ++i_)                       \
      _Pragma("unroll") for (int k_ = 0; k_ < 12; ++k_)                      \
          if ((ce) == i_ * 12 + k_) vout = PRa[i_][k_]; }

#define CELL(PRa, CUa, i, k, up, dn, lf, rt)                                 \
    PRa[i][k] = fmaf(CF[i][k],                                               \
                     fmaf(-4.f, CUa[i][k], ((up) + (dn)) + ((lf) + (rt))),   \
                     fmaf(2.f, CUa[i][k], -PRa[i][k]));

// One leapfrog substep. Shuffles issued first; the 10 shuffle-independent
// inner cells are computed before any shuffle result is consumed (explicit
// ILP to hide bpermute latency); perimeter cells follow.
#define SUBSTEP(CUa, PRa, t_)                                                \
{                                                                            \
    float tu[12], td[12], tl[3], tr[3];                                      \
    _Pragma("unroll") for (int k = 0; k < 12; ++k) {                         \
        tu[k] = __shfl(CUa[2][k], lup, 64);                                  \
        td[k] = __shfl(CUa[0][k], ldn, 64);                                  \
    }                                                                        \
    _Pragma("unroll") for (int i = 0; i < 3; ++i) {                          \
        tl[i] = __shfl(CUa[i][11], llf, 64);                                 \
        tr[i] = __shfl(CUa[i][0],  lrt, 64);                                 \
    }                                                                        \
    /* inner cells: i=1, k=1..10 — no shuffle dependency */                  \
    _Pragma("unroll") for (int k = 1; k < 11; ++k) {                         \
        CELL(PRa, CUa, 1, k, CUa[0][k], CUa[2][k],                           \
             CUa[1][k - 1], CUa[1][k + 1]);                                  \
    }                                                                        \
    /* row 0 (needs tu; tl/tr at col edges) */                               \
    _Pragma("unroll") for (int k = 0; k < 12; ++k) {                         \
        const float lf = (k == 0)  ? tl[0] : CUa[0][k - 1];                  \
        const float rt = (k == 11) ? tr[0] : CUa[0][k + 1];                  \
        CELL(PRa, CUa, 0, k, tu[k], CUa[1][k], lf, rt);                      \
    }                                                                        \
    /* row 2 (needs td) */                                                   \
    _Pragma("unroll") for (int k = 0; k < 12; ++k) {                         \
        const float lf = (k == 0)  ? tl[2] : CUa[2][k - 1];                  \
        const float rt = (k == 11) ? tr[2] : CUa[2][k + 1];                  \
        CELL(PRa, CUa, 2, k, CUa[1][k], td[k], lf, rt);                      \
    }                                                                        \
    /* row 1 edges */                                                        \
    CELL(PRa, CUa, 1, 0,  CUa[0][0],  CUa[2][0],  tl[1], CUa[1][1]);         \
    CELL(PRa, CUa, 1, 11, CUa[0][11], CUa[2][11], CUa[1][10], tr[1]);        \
    if (wsrc) {                                                              \
        const float a0 = sx[0 * NT + (t_)], a1 = sx[1 * NT + (t_)];          \
        const float a2 = sx[2 * NT + (t_)], a3 = sx[3 * NT + (t_)];          \
        _Pragma("unroll") for (int i = 0; i < 3; ++i)                        \
        _Pragma("unroll") for (int k = 0; k < 12; ++k) {                     \
            const int cc = i * 12 + k;                                       \
            if ((ms0 >> cc) & 1) PRa[i][k] += a0;                            \
            if ((ms1 >> cc) & 1) PRa[i][k] += a1;                            \
            if ((ms2 >> cc) & 1) PRa[i][k] += a2;                            \
            if ((ms3 >> cc) & 1) PRa[i][k] += a3;                            \
        }                                                                    \
    }                                                                        \
    if (wrec) {   /* per-lane receiver slots, direct stores */               \
        float vv;                                                            \
        if (rc0 >= 0) { PICK(PRa, rc0, vv); out[(t_) * NREC + rr0] = vv; }   \
        if (rc1 >= 0) { PICK(PRa, rc1, vv); out[(t_) * NREC + rr1] = vv; }   \
        if (rc2 >= 0) { PICK(PRa, rc2, vv); out[(t_) * NREC + rr2] = vv; }   \
        if (rc3 >= 0) { PICK(PRa, rc3, vv); out[(t_) * NREC + rr3] = vv; }   \
    }                                                                        \
}

// Pre-kernel: reset flags (kernel-boundary ordering publishes the zeros).
__global__ void reset_flags(int* flags) {
    flags[threadIdx.x] = 0;
}

// All-register temporal-blocked FDTD, coalesced LDS-staged global I/O.
// 256 blocks (16x16) x 256 threads, 1 block/CU. Each of 4 waves owns a
// 16x16-interior / 48x48-extended tile in VGPRs (lane = 3x12 patch). Halo
// exchange inside the 16-substep run is pure __shfl (no barriers). Per
// batch: spin on 8 neighbor flags, COALESCED reload of the ext tile into
// per-wave LDS staging (wave-local: no barrier), scatter-pick ring cells,
// 16 substeps, scatter store-stage + coalesced agent store-back, one
// __syncthreads (vmcnt drain), tid0 publishes flag.
__global__ __launch_bounds__(NTH, 1)
void wave_rs(const float* __restrict__ xsrc,   // (NSRC, NT)
             const float* __restrict__ vel,    // (NZ, NX)
             const int*   __restrict__ src_z,
             const int*   __restrict__ src_x,
             const int*   __restrict__ rec_z,
             const int*   __restrict__ rec_x,
             float*       __restrict__ out,    // (NT, NREC)
             u64*         __restrict__ slot0,  // (cur, prev) per cell
             u64*         __restrict__ slot1,
             int*         __restrict__ flags)  // (256)
{
    __shared__ float sx[NSRC * NT];
    __shared__ u64   sEx[4][EE * EPAD];        // per-wave staging, padded

    const int tid  = threadIdx.x;
    const int lane = tid & 63;
    const int wid  = tid >> 6;                 // wave 0..3
    const int me   = blockIdx.x;
    const int bz   = me >> 4, bx = me & 15;    // 16x16 block grid
    const int wz   = wid >> 1, wx = wid & 1;   // 2x2 wave grid in block
    const int tz0  = bz * 32 + wz * TT;        // wave interior origin
    const int tx0  = bx * 32 + wx * TT;
    const int ozw  = tz0 - KK;                 // wave extended-tile origin
    const int oxw  = tx0 - KK;
    const int pr   = lane >> 2;                // 0..15: rows 3pr..3pr+2
    const int pc   = lane & 3;                 // 0..3 : cols 12pc..12pc+11

    for (int i = tid; i < NSRC * NT; i += NTH) sx[i] = xsrc[i];
    __syncthreads();

    // ---- per-cell coefficient + per-source cell masks (bit = i*12+k) ----
    float CF[3][12];
    u64 ms0 = 0, ms1 = 0, ms2 = 0, ms3 = 0;
    {
        const int sz0 = src_z[0], sz1 = src_z[1], sz2 = src_z[2], sz3 = src_z[3];
        const int sx0 = src_x[0], sx1 = src_x[1], sx2 = src_x[2], sx3 = src_x[3];
#pragma unroll
        for (int i = 0; i < 3; ++i) {
            const int gz = ozw + 3 * pr + i;
#pragma unroll
            for (int k = 0; k < 12; ++k) {
                const int gxk = oxw + 12 * pc + k;
                const bool in = (gz >= 0 && gz < NZg && gxk >= 0 && gxk < NXg);
                const float v = in ? vel[gz * NXg + gxk] : 0.f;
                CF[i][k] = (v * DTC) * (v * DTC) / (DHC * DHC);
                const u64 bit = 1ull << (i * 12 + k);
                if (in && sz0 == gz && sx0 == gxk) ms0 |= bit;
                if (in && sz1 == gz && sx1 == gxk) ms1 |= bit;
                if (in && sz2 == gz && sx2 == gxk) ms2 |= bit;
                if (in && sz3 == gz && sx3 == gxk) ms3 |= bit;
            }
        }
    }
    const bool wsrc = __any((ms0 | ms1 | ms2 | ms3) != 0);

    // ---- per-lane receiver slots (named scalars; static indexing only) ----
    int rc0 = -1, rr0 = 0, rc1 = -1, rr1 = 0;
    int rc2 = -1, rr2 = 0, rc3 = -1, rr3 = 0;
    {
        int nsl = 0;
        for (int r = 0; r < NREC; ++r) {
            const int lz = rec_z[r] - ozw;
            const int lc = rec_x[r] - oxw;
            if (lz >= 3 * pr && lz < 3 * pr + 3 &&
                lc >= 12 * pc && lc < 12 * pc + 12 &&
                lz >= KK && lz < KK + TT && lc >= KK && lc < KK + TT) {
                const int ce = (lz - 3 * pr) * 12 + (lc - 12 * pc);
                if      (nsl == 0) { rc0 = ce; rr0 = r; }
                else if (nsl == 1) { rc1 = ce; rr1 = r; }
                else if (nsl == 2) { rc2 = ce; rr2 = r; }
                else if (nsl == 3) { rc3 = ce; rr3 = r; }
                ++nsl;
            }
        }
    }
    const bool wrec = __any(rc0 >= 0);

    // ---- neighbor-block spin mapping (lanes 0..8 of EVERY wave) ----
    bool havenb = false; int nbidx = 0;
    if (lane < 9 && lane != 4) {
        const int nz = bz + lane / 3 - 1, nx = bx + lane % 3 - 1;
        havenb = (nz >= 0 && nz < NBZ && nx >= 0 && nx < NBX);
        nbidx  = nz * NBX + nx;
    }

    const int lup = (lane - 4) & 63;   // lane holding my top halo row
    const int ldn = (lane + 4) & 63;
    const int llf = (lane - 1) & 63;
    const int lrt = (lane + 1) & 63;

    float X[3][12], Y[3][12];          // X=cur(even), Y=prev; roles alternate
#pragma unroll
    for (int i = 0; i < 3; ++i)
#pragma unroll
        for (int k = 0; k < 12; ++k) { X[i][k] = 0.f; Y[i][k] = 0.f; }

    for (int b = 0; b < NBATCH; ++b) {
        const u64* gin  = (b & 1) ? slot1 : slot0;
        u64*       gout = (b & 1) ? slot0 : slot1;

        if (b > 0) {
            // ---- per-wave spin on the 8 neighbor-block flags ----
            for (;;) {
                int fv = b;
                if (havenb) fv = ld_flag(&flags[nbidx]);
                if (__all(fv >= b)) break;
                __builtin_amdgcn_s_sleep(1);
            }
            // ---- COALESCED staged reload: linear ext-tile sweep ----
#pragma unroll
            for (int n = 0; n < NST; ++n) {
                const int c  = lane + (n << 6);      // 0..2303
                const int r  = c / EE;
                const int q  = c - r * EE;
                const int gz = ozw + r;
                const int gx = oxw + q;
                u64 v = 0ull;
                if (gz >= 0 && gz < NZg && gx >= 0 && gx < NXg)
                    v = ld_agent(&gin[gz * NXg + gx]);
                sEx[wid][r * EPAD + q] = v;          // coalesced ds_write
            }
            // ---- scatter-pick ring cells (wave-local, lgkm-ordered) ----
#pragma unroll
            for (int i = 0; i < 3; ++i) {
                const int lz = 3 * pr + i;
                const bool zin = (lz >= KK && lz < KK + TT);
#pragma unroll
                for (int k = 0; k < 12; ++k) {
                    const int lc = 12 * pc + k;
                    const bool inn = zin && lc >= KK && lc < KK + TT;
                    if (!inn) {
                        const float2 v = unpack2(sEx[wid][lz * EPAD + lc]);
                        X[i][k] = v.x;  Y[i][k] = v.y;
                    }
                }
            }
        }

        // ---- KK substeps, roles statically alternated, NO barriers ----
#pragma unroll 1
        for (int j = 0; j < KK; j += 2) {
            SUBSTEP(X, Y, b * KK + j);       // Y becomes u(t+1)
            SUBSTEP(Y, X, b * KK + j + 1);   // X becomes u(t+2)
        }

        // ---- store-back: scatter into compact staging, coalesced out ----
#pragma unroll
        for (int i = 0; i < 3; ++i) {
            const int lz = 3 * pr + i;
            if (lz >= KK && lz < KK + TT) {
#pragma unroll
                for (int k = 0; k < 12; ++k) {
                    const int lc = 12 * pc + k;
                    if (lc >= KK && lc < KK + TT)
                        sEx[wid][(lz - KK) * CPAD + (lc - KK)] =
                            pack2(X[i][k], Y[i][k]);
                }
            }
        }
#pragma unroll
        for (int n = 0; n < 4; ++n) {
            const int c = lane + (n << 6);           // 0..255
            const int r = c >> 4, q = c & 15;
            st_agent(&gout[(tz0 + r) * NXg + (tx0 + q)],
                     sEx[wid][r * CPAD + q]);        // coalesced global
        }
        __syncthreads();         // all 4 waves drain vmcnt before s_barrier
        if (tid == 0) st_flag(&flags[me], b + 1);   // publish whole block
    }
}

// Tripwire: runs ONLY if a launch is rejected; encodes the error code.
__global__ void launch_marker(float* out, float code) { out[0] = code; }

extern "C" void kernel_launch(void* const* d_in, const int* in_sizes, int n_in,
                              void* d_out, int out_size, void* d_ws, size_t ws_size,
                              hipStream_t stream) {
    const float* xsrc  = (const float*)d_in[0];
    const float* vel   = (const float*)d_in[1];
    const int*   src_z = (const int*)  d_in[2];
    const int*   src_x = (const int*)  d_in[3];
    const int*   rec_z = (const int*)  d_in[4];
    const int*   rec_x = (const int*)  d_in[5];
    float*       out   = (float*)d_out;

    u64* slot0 = (u64*)d_ws;
    u64* slot1 = slot0 + NZg * NXg;
    int* flags = (int*)(slot1 + NZg * NXg);

    (void)hipGetLastError();   // clear stale error state

    reset_flags<<<dim3(1), dim3(NBLK), 0, stream>>>(flags);

    wave_rs<<<dim3(NBLK), dim3(NTH), 0, stream>>>(
        xsrc, vel, src_z, src_x, rec_z, rec_x, out, slot0, slot1, flags);

    hipError_t err = hipGetLastError();
    if (err != hipSuccess) {
        launch_marker<<<dim3(1), dim3(1), 0, stream>>>(
            out, 1000.0f + (float)(int)err);
    }
}

// Round 14
// 3244.723 us; speedup vs baseline: 1.0427x; 1.0427x over previous
//
#include <hip/hip_runtime.h>

#define NZg  512
#define NXg  512
#define NT   1200
#define NSRC 4
#define NREC 512
#define DTC  0.001f
#define DHC  10.0f

#define TT     16            // interior tile per WAVE
#define KK     16            // substeps per batch (= halo width), even
#define NBATCH 75            // NT / KK
#define NTH    256           // 4 waves per block, 1 block/CU
#define NBZ    16            // block grid (16x16 blocks of 32x32 interior)
#define NBX    16
#define NBLK   256

typedef unsigned long long u64;

__device__ __forceinline__ u64 ld_agent(const u64* p) {
    return __hip_atomic_load(p, __ATOMIC_RELAXED, __HIP_MEMORY_SCOPE_AGENT);
}
__device__ __forceinline__ void st_agent(u64* p, u64 v) {
    __hip_atomic_store(p, v, __ATOMIC_RELAXED, __HIP_MEMORY_SCOPE_AGENT);
}
__device__ __forceinline__ int ld_flag(const int* p) {
    return __hip_atomic_load(p, __ATOMIC_RELAXED, __HIP_MEMORY_SCOPE_AGENT);
}
__device__ __forceinline__ void st_flag(int* p, int v) {
    __hip_atomic_store(p, v, __ATOMIC_RELAXED, __HIP_MEMORY_SCOPE_AGENT);
}
__device__ __forceinline__ u64 pack2(float a, float b) {
    union { float f[2]; u64 u; } c; c.f[0] = a; c.f[1] = b; return c.u;
}
__device__ __forceinline__ float2 unpack2(u64 v) {
    union { u64 u; float f[2]; } c; c.u = v; return make_float2(c.f[0], c.f[1]);
}

// DPP lane shifts within 16-lane rows (pure VALU — no LDS pipe, no lgkmcnt).
// row_shr:1 (0x111): result[lane] = src[lane-1];  lane%16==0 -> 0 (bound_ctrl)
// row_shl:1 (0x101): result[lane] = src[lane+1];  lane%16==15 -> 0
// Zeros land only on the eroded ext-tile rim (rows -1 / 48) — erosion-safe.
__device__ __forceinline__ float dpp_shr1(float x) {
    return __int_as_float(__builtin_amdgcn_update_dpp(
        0, __float_as_int(x), 0x111, 0xF, 0xF, true));
}
__device__ __forceinline__ float dpp_shl1(float x) {
    return __int_as_float(__builtin_amdgcn_update_dpp(
        0, __float_as_int(x), 0x101, 0xF, 0xF, true));
}

// Static-tree cell pick: ce is runtime, loop indices compile-time.
#define PICK(PRa, ce, vout)                                                  \
    { vout = 0.f;                                                            \
      _Pragma("unroll") for (int i_ = 0; i_ < 3; ++i_)                       \
      _Pragma("unroll") for (int k_ = 0; k_ < 12; ++k_)                      \
          if ((ce) == i_ * 12 + k_) vout = PRa[i_][k_]; }

#define CELL(PRa, CUa, i, k, up, dn, lf, rt)                                 \
    PRa[i][k] = fmaf(CF[i][k],                                               \
                     fmaf(-4.f, CUa[i][k], ((up) + (dn)) + ((lf) + (rt))),   \
                     fmaf(2.f, CUa[i][k], -PRa[i][k]));

// One leapfrog substep. 6 bpermutes (left/right halo cols) issued FIRST,
// vertical halos via 24 DPP movs (VALU), ~500cy of bpermute-independent
// cell FMAs between bpermute issue and first tl/tr consumption.
#define SUBSTEP(CUa, PRa, t_)                                                \
{                                                                            \
    float tl[3], tr[3];                                                      \
    _Pragma("unroll") for (int i = 0; i < 3; ++i) {                          \
        tl[i] = __shfl(CUa[i][11], llf, 64);                                 \
        tr[i] = __shfl(CUa[i][0],  lrt, 64);                                 \
    }                                                                        \
    float tu[12], td[12];                                                    \
    _Pragma("unroll") for (int k = 0; k < 12; ++k) {                         \
        tu[k] = dpp_shr1(CUa[2][k]);                                         \
        td[k] = dpp_shl1(CUa[0][k]);                                         \
    }                                                                        \
    /* bpermute-independent bulk: rows 0..2, k=1..10 */                      \
    _Pragma("unroll") for (int k = 1; k < 11; ++k) {                         \
        CELL(PRa, CUa, 1, k, CUa[0][k], CUa[2][k],                           \
             CUa[1][k - 1], CUa[1][k + 1]);                                  \
    }                                                                        \
    _Pragma("unroll") for (int k = 1; k < 11; ++k) {                         \
        CELL(PRa, CUa, 0, k, tu[k], CUa[1][k],                               \
             CUa[0][k - 1], CUa[0][k + 1]);                                  \
    }                                                                        \
    _Pragma("unroll") for (int k = 1; k < 11; ++k) {                         \
        CELL(PRa, CUa, 2, k, CUa[1][k], td[k],                               \
             CUa[2][k - 1], CUa[2][k + 1]);                                  \
    }                                                                        \
    /* edge cells (consume tl/tr) last */                                    \
    CELL(PRa, CUa, 0, 0,  tu[0],      CUa[1][0],  tl[0], CUa[0][1]);         \
    CELL(PRa, CUa, 0, 11, tu[11],     CUa[1][11], CUa[0][10], tr[0]);        \
    CELL(PRa, CUa, 1, 0,  CUa[0][0],  CUa[2][0],  tl[1], CUa[1][1]);         \
    CELL(PRa, CUa, 1, 11, CUa[0][11], CUa[2][11], CUa[1][10], tr[1]);        \
    CELL(PRa, CUa, 2, 0,  CUa[1][0],  td[0],      tl[2], CUa[2][1]);         \
    CELL(PRa, CUa, 2, 11, CUa[1][11], td[11],     CUa[2][10], tr[2]);        \
    if (wsrc) {                                                              \
        const float a0 = sx[0 * NT + (t_)], a1 = sx[1 * NT + (t_)];          \
        const float a2 = sx[2 * NT + (t_)], a3 = sx[3 * NT + (t_)];          \
        _Pragma("unroll") for (int i = 0; i < 3; ++i)                        \
        _Pragma("unroll") for (int k = 0; k < 12; ++k) {                     \
            const int cc = i * 12 + k;                                       \
            if ((ms0 >> cc) & 1) PRa[i][k] += a0;                            \
            if ((ms1 >> cc) & 1) PRa[i][k] += a1;                            \
            if ((ms2 >> cc) & 1) PRa[i][k] += a2;                            \
            if ((ms3 >> cc) & 1) PRa[i][k] += a3;                            \
        }                                                                    \
    }                                                                        \
    if (wrec) {   /* per-lane receiver slots, direct stores */               \
        float vv;                                                            \
        if (rc0 >= 0) { PICK(PRa, rc0, vv); out[(t_) * NREC + rr0] = vv; }   \
        if (rc1 >= 0) { PICK(PRa, rc1, vv); out[(t_) * NREC + rr1] = vv; }   \
        if (rc2 >= 0) { PICK(PRa, rc2, vv); out[(t_) * NREC + rr2] = vv; }   \
        if (rc3 >= 0) { PICK(PRa, rc3, vv); out[(t_) * NREC + rr3] = vv; }   \
    }                                                                        \
}

// Pre-kernel: reset flags (kernel-boundary ordering publishes the zeros).
__global__ void reset_flags(int* flags) {
    flags[threadIdx.x] = 0;
}

// All-register temporal-blocked FDTD; vertical halo exchange via DPP (VALU),
// horizontal via 6 bpermutes. 256 blocks (16x16) x 256 threads, 1 block/CU.
// Lane layout TRANSPOSED vs r12: pr = lane&15 (DPP-row position), pc =
// lane>>4 — so lane±1 (same DPP row) = vertical neighbor patch.
__global__ __launch_bounds__(NTH, 1)
void wave_rd(const float* __restrict__ xsrc,   // (NSRC, NT)
             const float* __restrict__ vel,    // (NZ, NX)
             const int*   __restrict__ src_z,
             const int*   __restrict__ src_x,
             const int*   __restrict__ rec_z,
             const int*   __restrict__ rec_x,
             float*       __restrict__ out,    // (NT, NREC)
             u64*         __restrict__ slot0,  // (cur, prev) per cell
             u64*         __restrict__ slot1,
             int*         __restrict__ flags)  // (256)
{
    __shared__ float sx[NSRC * NT];

    const int tid  = threadIdx.x;
    const int lane = tid & 63;
    const int wid  = tid >> 6;                 // wave 0..3
    const int me   = blockIdx.x;
    const int bz   = me >> 4, bx = me & 15;    // 16x16 block grid
    const int wz   = wid >> 1, wx = wid & 1;   // 2x2 wave grid in block
    const int tz0  = bz * 32 + wz * TT;        // wave interior origin
    const int tx0  = bx * 32 + wx * TT;
    const int ozw  = tz0 - KK;                 // wave extended-tile origin
    const int oxw  = tx0 - KK;
    const int pr   = lane & 15;                // 0..15: rows 3pr..3pr+2
    const int pc   = lane >> 4;                // 0..3 : cols 12pc..12pc+11

    for (int i = tid; i < NSRC * NT; i += NTH) sx[i] = xsrc[i];
    __syncthreads();

    // ---- per-cell coefficient + per-source cell masks (bit = i*12+k) ----
    float CF[3][12];
    u64 ms0 = 0, ms1 = 0, ms2 = 0, ms3 = 0;
    {
        const int sz0 = src_z[0], sz1 = src_z[1], sz2 = src_z[2], sz3 = src_z[3];
        const int sx0 = src_x[0], sx1 = src_x[1], sx2 = src_x[2], sx3 = src_x[3];
#pragma unroll
        for (int i = 0; i < 3; ++i) {
            const int gz = ozw + 3 * pr + i;
#pragma unroll
            for (int k = 0; k < 12; ++k) {
                const int gxk = oxw + 12 * pc + k;
                const bool in = (gz >= 0 && gz < NZg && gxk >= 0 && gxk < NXg);
                const float v = in ? vel[gz * NXg + gxk] : 0.f;
                CF[i][k] = (v * DTC) * (v * DTC) / (DHC * DHC);
                const u64 bit = 1ull << (i * 12 + k);
                if (in && sz0 == gz && sx0 == gxk) ms0 |= bit;
                if (in && sz1 == gz && sx1 == gxk) ms1 |= bit;
                if (in && sz2 == gz && sx2 == gxk) ms2 |= bit;
                if (in && sz3 == gz && sx3 == gxk) ms3 |= bit;
            }
        }
    }
    const bool wsrc = __any((ms0 | ms1 | ms2 | ms3) != 0);

    // ---- per-lane receiver slots (named scalars; static indexing only) ----
    int rc0 = -1, rr0 = 0, rc1 = -1, rr1 = 0;
    int rc2 = -1, rr2 = 0, rc3 = -1, rr3 = 0;
    {
        int nsl = 0;
        for (int r = 0; r < NREC; ++r) {
            const int lz = rec_z[r] - ozw;
            const int lc = rec_x[r] - oxw;
            if (lz >= 3 * pr && lz < 3 * pr + 3 &&
                lc >= 12 * pc && lc < 12 * pc + 12 &&
                lz >= KK && lz < KK + TT && lc >= KK && lc < KK + TT) {
                const int ce = (lz - 3 * pr) * 12 + (lc - 12 * pc);
                if      (nsl == 0) { rc0 = ce; rr0 = r; }
                else if (nsl == 1) { rc1 = ce; rr1 = r; }
                else if (nsl == 2) { rc2 = ce; rr2 = r; }
                else if (nsl == 3) { rc3 = ce; rr3 = r; }
                ++nsl;
            }
        }
    }
    const bool wrec = __any(rc0 >= 0);

    // ---- neighbor-block spin mapping (lanes 0..8 of EVERY wave) ----
    bool havenb = false; int nbidx = 0;
    if (lane < 9 && lane != 4) {
        const int nz = bz + lane / 3 - 1, nx = bx + lane % 3 - 1;
        havenb = (nz >= 0 && nz < NBZ && nx >= 0 && nx < NBX);
        nbidx  = nz * NBX + nx;
    }

    const int llf = (lane - 16) & 63;  // lane holding my left halo col
    const int lrt = (lane + 16) & 63;  // lane holding my right halo col

    float X[3][12], Y[3][12];          // X=cur(even), Y=prev; roles alternate
#pragma unroll
    for (int i = 0; i < 3; ++i)
#pragma unroll
        for (int k = 0; k < 12; ++k) { X[i][k] = 0.f; Y[i][k] = 0.f; }

    for (int b = 0; b < NBATCH; ++b) {
        const u64* gin  = (b & 1) ? slot1 : slot0;
        u64*       gout = (b & 1) ? slot0 : slot1;

        if (b > 0) {
            // ---- per-wave spin on the 8 neighbor-block flags ----
            for (;;) {
                int fv = b;
                if (havenb) fv = ld_flag(&flags[nbidx]);
                if (__all(fv >= b)) break;
                __builtin_amdgcn_s_sleep(1);
            }
            // ---- reload ring cells (own interior persists in registers) ----
#pragma unroll
            for (int i = 0; i < 3; ++i) {
                const int lz = 3 * pr + i;
                const int gz = ozw + lz;
                const bool zin = (lz >= KK && lz < KK + TT);
#pragma unroll
                for (int k = 0; k < 12; ++k) {
                    const int lc = 12 * pc + k;
                    const bool inn = zin && lc >= KK && lc < KK + TT;
                    if (!inn) {
                        const int gxk = oxw + lc;
                        if (gz >= 0 && gz < NZg && gxk >= 0 && gxk < NXg) {
                            const float2 v = unpack2(ld_agent(&gin[gz * NXg + gxk]));
                            X[i][k] = v.x;  Y[i][k] = v.y;
                        } else { X[i][k] = 0.f; Y[i][k] = 0.f; }
                    }
                }
            }
        }

        // ---- KK substeps, roles statically alternated, NO barriers ----
#pragma unroll 1
        for (int j = 0; j < KK; j += 2) {
            SUBSTEP(X, Y, b * KK + j);       // Y becomes u(t+1)
            SUBSTEP(Y, X, b * KK + j + 1);   // X becomes u(t+2)
        }

        // ---- store 16x16 interior (always in-domain) ----
#pragma unroll
        for (int i = 0; i < 3; ++i) {
            const int lz = 3 * pr + i;
            if (lz >= KK && lz < KK + TT) {
                const int gz = ozw + lz;
#pragma unroll
                for (int k = 0; k < 12; ++k) {
                    const int lc = 12 * pc + k;
                    if (lc >= KK && lc < KK + TT)
                        st_agent(&gout[gz * NXg + oxw + lc],
                                 pack2(X[i][k], Y[i][k]));
                }
            }
        }
        __syncthreads();         // all 4 waves drain vmcnt before s_barrier
        if (tid == 0) st_flag(&flags[me], b + 1);   // publish whole block
    }
}

// Tripwire: runs ONLY if a launch is rejected; encodes the error code.
__global__ void launch_marker(float* out, float code) { out[0] = code; }

extern "C" void kernel_launch(void* const* d_in, const int* in_sizes, int n_in,
                              void* d_out, int out_size, void* d_ws, size_t ws_size,
                              hipStream_t stream) {
    const float* xsrc  = (const float*)d_in[0];
    const float* vel   = (const float*)d_in[1];
    const int*   src_z = (const int*)  d_in[2];
    const int*   src_x = (const int*)  d_in[3];
    const int*   rec_z = (const int*)  d_in[4];
    const int*   rec_x = (const int*)  d_in[5];
    float*       out   = (float*)d_out;

    u64* slot0 = (u64*)d_ws;
    u64* slot1 = slot0 + NZg * NXg;
    int* flags = (int*)(slot1 + NZg * NXg);

    (void)hipGetLastError();   // clear stale error state

    reset_flags<<<dim3(1), dim3(NBLK), 0, stream>>>(flags);

    wave_rd<<<dim3(NBLK), dim3(NTH), 0, stream>>>(
        xsrc, vel, src_z, src_x, rec_z, rec_x, out, slot0, slot1, flags);

    hipError_t err = hipGetLastError();
    if (err != hipSuccess) {
        launch_marker<<<dim3(1), dim3(1), 0, stream>>>(
            out, 1000.0f + (float)(int)err);
    }
}